// Round 11
// baseline (208.628 us; speedup 1.0000x reference)
//
#include <hip/hip_runtime.h>
#include <hip/hip_bf16.h>
#include <cmath>

// GATv2 encoder, 3 layers, d=64, f32 in/out.
//   1. dst-CSR build via two-level partition (coarse 1024-dst buckets ->
//      per-coarse-bucket fine CSR; csr_src as ushort), then a DESCENDING
//      counting sort of nodes by degree (perm): equal-degree nodes share a
//      wave (no divergence), heavy blocks launch first.
//   2. per layer: persistent transform (W in registers, grid-stride) ->
//      xlh/xrh bf16 tables; edge aggregation: 4 nodes/wave, 2 octets x 8
//      lanes per node group, ONE EDGE PER OCTET (uint4 = 8 bf16/lane gathers,
//      3-shfl dot reduce), online softmax with defer-rescale, unrolled
//      full-16 batches, fused bias+ReLU+residual.

#define D 64
#define CB 10              // coarse bucket = 1024 dsts (dst >> CB); N <= 65536
#define NBLK 512           // persistent blocks for coarse hist/scatter

// ---------------- CSR build ----------------

__global__ __launch_bounds__(256) void hist_coarse_kernel(
    const int* __restrict__ ei, int* __restrict__ ghist, int E, int N, int NC) {
  __shared__ int h[64];
  int tid = threadIdx.x, blk = blockIdx.x;
  if (tid < 64) h[tid] = 0;
  __syncthreads();
  for (int eid = blk * 256 + tid; eid < E + N; eid += NBLK * 256) {
    int d = (eid < E) ? ei[E + eid] : (eid - E);
    atomicAdd(&h[d >> CB], 1);
  }
  __syncthreads();
  if (tid < NC) ghist[tid * NBLK + blk] = h[tid];
}

__global__ __launch_bounds__(1024) void scan_coarse_kernel(
    int* __restrict__ g, int* __restrict__ cbase, int* __restrict__ dh,
    int M, int NC, int EP) {
  int tid = threadIdx.x;
  if (tid < 64) dh[tid] = 0;              // degree-histogram init (used later)
  int chunk = (M + 1023) / 1024;
  int beg = tid * chunk;
  int end = min(M, beg + chunk);
  int sum = 0;
  for (int i = beg; i < end; ++i) sum += g[i];
  int lane = tid & 63, w = tid >> 6;
  int v = sum;
#pragma unroll
  for (int o = 1; o < 64; o <<= 1) {
    int t = __shfl_up(v, o, 64);
    if (lane >= o) v += t;
  }
  __shared__ int wsum[16], woff[16];
  if (lane == 63) wsum[w] = v;
  __syncthreads();
  if (tid == 0) { int r = 0; for (int i = 0; i < 16; ++i) { woff[i] = r; r += wsum[i]; } }
  __syncthreads();
  int run = woff[w] + (v - sum);
  for (int i = beg; i < end; ++i) {
    int old = g[i];
    g[i] = run;
    if ((i & (NBLK - 1)) == 0) cbase[i / NBLK] = run;
    run += old;
  }
  if (tid == 0) cbase[NC] = EP;
}

// rec = (dst&1023)<<16 | src.
__global__ __launch_bounds__(256) void scatter_coarse_kernel(
    const int* __restrict__ ei, const int* __restrict__ g,
    unsigned* __restrict__ rec, int E, int N, int NC) {
  __shared__ int cur[64];
  int tid = threadIdx.x, blk = blockIdx.x;
  if (tid < NC) cur[tid] = g[tid * NBLK + blk];
  __syncthreads();
  for (int eid = blk * 256 + tid; eid < E + N; eid += NBLK * 256) {
    int s, d;
    if (eid < E) { s = ei[eid]; d = ei[E + eid]; }
    else         { s = d = eid - E; }
    int pos = atomicAdd(&cur[d >> CB], 1);
    rec[pos] = ((unsigned)(d & ((1 << CB) - 1)) << 16) | (unsigned)s;
  }
}

__global__ __launch_bounds__(1024) void buildcsr2_kernel(
    const unsigned* __restrict__ rec, const int* __restrict__ cbase,
    int* __restrict__ rowptr, unsigned short* __restrict__ csr_src,
    int* __restrict__ dh, int N, int EP) {
  int c = blockIdx.x, tid = threadIdx.x;
  int bb = cbase[c], be = cbase[c + 1];
  __shared__ int hist[1024], cur[1024];
  __shared__ int dloc[64];
  hist[tid] = 0;
  if (tid < 64) dloc[tid] = 0;
  __syncthreads();
  for (int p = bb + tid; p < be; p += 1024)
    atomicAdd(&hist[rec[p] >> 16], 1);
  __syncthreads();
  int dv = hist[tid];
  int lane = tid & 63, w = tid >> 6;
  int inc = dv;
#pragma unroll
  for (int o = 1; o < 64; o <<= 1) {
    int t = __shfl_up(inc, o, 64);
    if (lane >= o) inc += t;
  }
  __shared__ int wsum[16], woff[16];
  if (lane == 63) wsum[w] = inc;
  __syncthreads();
  if (tid == 0) { int r = 0; for (int i = 0; i < 16; ++i) { woff[i] = r; r += wsum[i]; } }
  __syncthreads();
  int excl = woff[w] + inc - dv;
  cur[tid] = excl;
  int node = (c << CB) + tid;
  if (node < N) {
    rowptr[node] = bb + excl;
    atomicAdd(&dloc[min(dv, 63)], 1);
  }
  if (c == 0 && tid == 0) rowptr[N] = EP;
  __syncthreads();
  if (tid < 64 && dloc[tid]) atomicAdd(&dh[tid], dloc[tid]);
  for (int p = bb + tid; p < be; p += 1024) {
    unsigned r = rec[p];
    int pos = bb + atomicAdd(&cur[r >> 16], 1);
    csr_src[pos] = (unsigned short)(r & 0xFFFFu);
  }
}

// DESCENDING exclusive scan of the 64 degree bins -> dcur.
__global__ __launch_bounds__(64) void deg_scan_kernel(
    const int* __restrict__ dh, int* __restrict__ dcur) {
  int tid = threadIdx.x;          // position in descending order
  int bin = 63 - tid;
  int v = dh[bin];
  int orig = v;
#pragma unroll
  for (int o = 1; o < 64; o <<= 1) {
    int t = __shfl_up(v, o, 64);
    if (tid >= o) v += t;
  }
  dcur[bin] = v - orig;
}

__global__ __launch_bounds__(256) void deg_scatter_kernel(
    const int* __restrict__ rowptr, int* __restrict__ dcur,
    int* __restrict__ perm, int N) {
  __shared__ int cnt[64], base[64], cur2[64];
  int tid = threadIdx.x;
  if (tid < 64) { cnt[tid] = 0; cur2[tid] = 0; }
  __syncthreads();
  int i = blockIdx.x * 256 + tid;
  int bin = 0;
  bool act = (i < N);
  if (act) {
    int deg = rowptr[i + 1] - rowptr[i];
    bin = min(deg, 63);
    atomicAdd(&cnt[bin], 1);
  }
  __syncthreads();
  if (tid < 64 && cnt[tid]) base[tid] = atomicAdd(&dcur[tid], cnt[tid]);
  __syncthreads();
  if (act) {
    int pos = base[bin] + atomicAdd(&cur2[bin], 1);
    perm[pos] = i;
  }
}

// ---------------- transform: xlh = bf16(h@Wl+bl), xrh = bf16(h@Wr+br) -------

__device__ __forceinline__ unsigned short f2bf(float f) {
  unsigned u = __float_as_uint(f);
  return (unsigned short)((u + 0x7FFFu + ((u >> 16) & 1u)) >> 16);  // RNE
}
__device__ __forceinline__ float bflo(unsigned u) { return __uint_as_float(u << 16); }
__device__ __forceinline__ float bfhi(unsigned u) { return __uint_as_float(u & 0xFFFF0000u); }

__global__ __launch_bounds__(256) void transform_kernel(
    const float* __restrict__ h,
    const float* __restrict__ Wl, const float* __restrict__ bl,
    const float* __restrict__ Wr, const float* __restrict__ br,
    unsigned short* __restrict__ xlh, unsigned short* __restrict__ xrh,
    int N, int ntiles) {
  __shared__ float hs[16][D];
  int tid = threadIdx.x;
  int j = tid & 63;
  float wl[D], wr[D];
#pragma unroll
  for (int k = 0; k < D; ++k) {           // coalesced: lane j reads column j
    wl[k] = Wl[k * D + j];
    wr[k] = Wr[k * D + j];
  }
  float blj = bl[j], brj = br[j];
  int nl = tid >> 6;
  int lr = tid >> 4, lc = (tid & 15) * 4; // float4 tile loader mapping
  for (int tile = blockIdx.x; tile < ntiles; tile += gridDim.x) {
    int node0 = tile * 16;
    __syncthreads();                      // hs safe to overwrite
    int n = node0 + lr;
    float4 hv4 = make_float4(0.f, 0.f, 0.f, 0.f);
    if (n < N) hv4 = *reinterpret_cast<const float4*>(&h[(size_t)n * D + lc]);
    *reinterpret_cast<float4*>(&hs[lr][lc]) = hv4;
    __syncthreads();
    for (int g = 0; g < 4; ++g) {
      int local = nl * 4 + g;
      int nn = node0 + local;
      float al = blj, ar = brj;
#pragma unroll
      for (int k4 = 0; k4 < D / 4; ++k4) {
        float4 hv = *reinterpret_cast<const float4*>(&hs[local][k4 * 4]);
        al = fmaf(hv.x, wl[k4 * 4 + 0], al);
        ar = fmaf(hv.x, wr[k4 * 4 + 0], ar);
        al = fmaf(hv.y, wl[k4 * 4 + 1], al);
        ar = fmaf(hv.y, wr[k4 * 4 + 1], ar);
        al = fmaf(hv.z, wl[k4 * 4 + 2], al);
        ar = fmaf(hv.z, wr[k4 * 4 + 2], ar);
        al = fmaf(hv.w, wl[k4 * 4 + 3], al);
        ar = fmaf(hv.w, wr[k4 * 4 + 3], ar);
      }
      if (nn < N) {
        xlh[(size_t)nn * D + j] = f2bf(al);
        xrh[(size_t)nn * D + j] = f2bf(ar);
      }
    }
  }
}

// ---------------- edge aggregation ----------------
// Wave = 4 equal-degree nodes; per node a 16-lane group = 2 octets x 8 lanes.
// Each octet owns one edge at a time, 8 features/lane (uint4 = 8 bf16 gather).
// Per 4-edge chunk: 2 wave loads, 3-shfl dot reduce, 1 cross-octet max,
// 1 cross-octet sum, 2 exps. Full-16 batches unrolled (uniform via deg sort).

__global__ __launch_bounds__(256, 6) void edge_kernel(
    const unsigned short* __restrict__ xlh, const unsigned short* __restrict__ xrh,
    const float* __restrict__ h_in, const int* __restrict__ rowptr,
    const unsigned short* __restrict__ csr_src, const int* __restrict__ perm,
    const float* __restrict__ att, const float* __restrict__ bias,
    float* __restrict__ h_out, int N) {
  int wv = (blockIdx.x * blockDim.x + threadIdx.x) >> 6;
  int lane = threadIdx.x & 63;
  int g = lane >> 4;            // node group 0..3
  int o = (lane >> 3) & 1;      // octet within group
  int f = lane & 7;             // feature octet: feats f*8 .. f*8+7
  int l16 = lane & 15;
  int idx = wv * 4 + g;
  if (idx >= N) return;
  int v = perm[idx];            // equal-degree within the wave
  // xr features (bf16 -> f32)
  uint4 xq = *reinterpret_cast<const uint4*>(&xrh[(size_t)v * D + f * 8]);
  float xr8[8];
  xr8[0] = bflo(xq.x); xr8[1] = bfhi(xq.x);
  xr8[2] = bflo(xq.y); xr8[3] = bfhi(xq.y);
  xr8[4] = bflo(xq.z); xr8[5] = bfhi(xq.z);
  xr8[6] = bflo(xq.w); xr8[7] = bfhi(xq.w);
  float4 atA = *reinterpret_cast<const float4*>(&att[f * 8]);
  float4 atB = *reinterpret_cast<const float4*>(&att[f * 8 + 4]);
  // early epilogue loads: latency hides under the edge loop
  float4 bA = *reinterpret_cast<const float4*>(&bias[f * 8]);
  float4 bB = *reinterpret_cast<const float4*>(&bias[f * 8 + 4]);
  float4 hA = *reinterpret_cast<const float4*>(&h_in[(size_t)v * D + f * 8]);
  float4 hB = *reinterpret_cast<const float4*>(&h_in[(size_t)v * D + f * 8 + 4]);
  int beg = rowptr[v], end = rowptr[v + 1];
  int deg = end - beg;          // >= 1 (self-loop)
  int glane0 = g << 4;
  float m = -INFINITY, s = 0.f;
  float acc[8];
#pragma unroll
  for (int i = 0; i < 8; ++i) acc[i] = 0.f;
  int foff = f << 3;
  int us = csr_src[min(beg + l16, end - 1)];   // 16 srcs per group (coalesced)

#define EDGE_CHUNK(SC, NT)                                                    \
  {                                                                           \
    int e0 = (SC) + o, e1 = (SC) + 2 + o;                                     \
    unsigned u0 = (unsigned)__shfl(us_cur, glane0 + e0, 64);                  \
    unsigned u1 = (unsigned)__shfl(us_cur, glane0 + e1, 64);                  \
    uint4 q0 = *reinterpret_cast<const uint4*>(&xlh[(u0 << 6) + foff]);       \
    uint4 q1 = *reinterpret_cast<const uint4*>(&xlh[(u1 << 6) + foff]);       \
    float x0[8], x1[8];                                                       \
    x0[0] = bflo(q0.x); x0[1] = bfhi(q0.x); x0[2] = bflo(q0.y);               \
    x0[3] = bfhi(q0.y); x0[4] = bflo(q0.z); x0[5] = bfhi(q0.z);               \
    x0[6] = bflo(q0.w); x0[7] = bfhi(q0.w);                                   \
    x1[0] = bflo(q1.x); x1[1] = bfhi(q1.x); x1[2] = bflo(q1.y);               \
    x1[3] = bfhi(q1.y); x1[4] = bflo(q1.z); x1[5] = bfhi(q1.z);               \
    x1[6] = bflo(q1.w); x1[7] = bfhi(q1.w);                                   \
    float p0, p1;                                                             \
    {                                                                         \
      float t, d0 = 0.f, d1 = 0.f;                                            \
      t = x0[0] + xr8[0]; t = fmaxf(t, 0.2f * t); d0 = t * atA.x;             \
      t = x0[1] + xr8[1]; t = fmaxf(t, 0.2f * t); d0 = fmaf(t, atA.y, d0);    \
      t = x0[2] + xr8[2]; t = fmaxf(t, 0.2f * t); d0 = fmaf(t, atA.z, d0);    \
      t = x0[3] + xr8[3]; t = fmaxf(t, 0.2f * t); d0 = fmaf(t, atA.w, d0);    \
      t = x0[4] + xr8[4]; t = fmaxf(t, 0.2f * t); d0 = fmaf(t, atB.x, d0);    \
      t = x0[5] + xr8[5]; t = fmaxf(t, 0.2f * t); d0 = fmaf(t, atB.y, d0);    \
      t = x0[6] + xr8[6]; t = fmaxf(t, 0.2f * t); d0 = fmaf(t, atB.z, d0);    \
      t = x0[7] + xr8[7]; t = fmaxf(t, 0.2f * t); d0 = fmaf(t, atB.w, d0);    \
      t = x1[0] + xr8[0]; t = fmaxf(t, 0.2f * t); d1 = t * atA.x;             \
      t = x1[1] + xr8[1]; t = fmaxf(t, 0.2f * t); d1 = fmaf(t, atA.y, d1);    \
      t = x1[2] + xr8[2]; t = fmaxf(t, 0.2f * t); d1 = fmaf(t, atA.z, d1);    \
      t = x1[3] + xr8[3]; t = fmaxf(t, 0.2f * t); d1 = fmaf(t, atA.w, d1);    \
      t = x1[4] + xr8[4]; t = fmaxf(t, 0.2f * t); d1 = fmaf(t, atB.x, d1);    \
      t = x1[5] + xr8[5]; t = fmaxf(t, 0.2f * t); d1 = fmaf(t, atB.y, d1);    \
      t = x1[6] + xr8[6]; t = fmaxf(t, 0.2f * t); d1 = fmaf(t, atB.z, d1);    \
      t = x1[7] + xr8[7]; t = fmaxf(t, 0.2f * t); d1 = fmaf(t, atB.w, d1);    \
      d0 += __shfl_xor(d0, 1, 64); d1 += __shfl_xor(d1, 1, 64);               \
      d0 += __shfl_xor(d0, 2, 64); d1 += __shfl_xor(d1, 2, 64);               \
      d0 += __shfl_xor(d0, 4, 64); d1 += __shfl_xor(d1, 4, 64);               \
      p0 = (e0 < (NT)) ? d0 : -INFINITY;                                      \
      p1 = (e1 < (NT)) ? d1 : -INFINITY;                                      \
    }                                                                         \
    float pm = fmaxf(p0, p1);                                                 \
    pm = fmaxf(pm, __shfl_xor(pm, 8, 64));                                    \
    if (pm > m + 8.0f) {                    /* defer-rescale (group-uniform)*/ \
      float a = __expf(m - pm);             /* first chunk: exp(-inf)=0 */     \
      s *= a;                                                                 \
      _Pragma("unroll")                                                       \
      for (int i = 0; i < 8; ++i) acc[i] *= a;                                \
      m = pm;                                                                 \
    }                                                                         \
    float w0 = __expf(p0 - m);              /* bounded by e^8; invalid -> 0 */ \
    float w1 = __expf(p1 - m);                                                \
    float sw = w0 + w1;                                                       \
    sw += __shfl_xor(sw, 8, 64);                                              \
    s += sw;                                                                  \
    _Pragma("unroll")                                                         \
    for (int i = 0; i < 8; ++i)                                               \
      acc[i] = fmaf(w0, x0[i], fmaf(w1, x1[i], acc[i]));                      \
  }

  for (int base = 0; base < deg; base += 16) {
    int us_cur = us;
    if (base + 16 < deg)                       // prefetch next batch's indices
      us = csr_src[min(beg + base + 16 + l16, end - 1)];
    int nt = min(16, deg - base);
    if (nt == 16) {                            // uniform fast path (deg sort)
      EDGE_CHUNK(0, 16)
      EDGE_CHUNK(4, 16)
      EDGE_CHUNK(8, 16)
      EDGE_CHUNK(12, 16)
    } else {
      for (int sc = 0; sc < nt; sc += 4) {
        EDGE_CHUNK(sc, nt)
      }
    }
  }
#undef EDGE_CHUNK

  // combine octets (same feature slots, different edge subsets)
#pragma unroll
  for (int i = 0; i < 8; ++i) acc[i] += __shfl_xor(acc[i], 8, 64);
  if (o == 0) {                               // 8 lanes/node write 256B
    float inv = 1.f / s;
    float4 oA, oB;
    oA.x = fmaxf(acc[0] * inv + bA.x, 0.f) + hA.x;
    oA.y = fmaxf(acc[1] * inv + bA.y, 0.f) + hA.y;
    oA.z = fmaxf(acc[2] * inv + bA.z, 0.f) + hA.z;
    oA.w = fmaxf(acc[3] * inv + bA.w, 0.f) + hA.w;
    oB.x = fmaxf(acc[4] * inv + bB.x, 0.f) + hB.x;
    oB.y = fmaxf(acc[5] * inv + bB.y, 0.f) + hB.y;
    oB.z = fmaxf(acc[6] * inv + bB.z, 0.f) + hB.z;
    oB.w = fmaxf(acc[7] * inv + bB.w, 0.f) + hB.w;
    float* op = &h_out[(size_t)v * D + f * 8];
    *reinterpret_cast<float4*>(op) = oA;
    *reinterpret_cast<float4*>(op + 4) = oB;
  }
}

// ---------------- launch ----------------

extern "C" void kernel_launch(void* const* d_in, const int* in_sizes, int n_in,
                              void* d_out, int out_size, void* d_ws, size_t ws_size,
                              hipStream_t stream) {
  const float* x    = (const float*)d_in[0];
  const int*   ei   = (const int*)d_in[1];
  const float* Wl   = (const float*)d_in[2];
  const float* bl   = (const float*)d_in[3];
  const float* Wr   = (const float*)d_in[4];
  const float* br   = (const float*)d_in[5];
  const float* att  = (const float*)d_in[6];
  const float* bias = (const float*)d_in[7];

  int N = in_sizes[0] / D;
  int E = in_sizes[1] / 2;
  int L = in_sizes[2] / (D * D);
  int EP = E + N;
  int NC = (N + (1 << CB) - 1) >> CB;   // coarse buckets (<= 64)
  int M = NC * NBLK;

  float* hA = (float*)d_ws;
  float* hB = hA + (size_t)N * D;
  unsigned short* xlh = (unsigned short*)(hB + (size_t)N * D);
  unsigned short* xrh = xlh + (size_t)N * D;
  unsigned* rec = (unsigned*)(xrh + (size_t)N * D);
  unsigned short* csr_src = (unsigned short*)(rec + EP);
  int* rowptr   = (int*)(csr_src + ((EP + 1) & ~1));
  int* ghist    = rowptr + (N + 1);
  int* cbase    = ghist + M;
  int* dh       = cbase + (NC + 1);
  int* dcur     = dh + 64;
  int* perm     = dcur + 64;

  // CSR build + degree sort (graph is layer-invariant: once per call; every
  // slot used is rewritten each call, so no memsets needed)
  hist_coarse_kernel<<<NBLK, 256, 0, stream>>>(ei, ghist, E, N, NC);
  scan_coarse_kernel<<<1, 1024, 0, stream>>>(ghist, cbase, dh, M, NC, EP);
  scatter_coarse_kernel<<<NBLK, 256, 0, stream>>>(ei, ghist, rec, E, N, NC);
  buildcsr2_kernel<<<NC, 1024, 0, stream>>>(rec, cbase, rowptr, csr_src, dh, N, EP);
  deg_scan_kernel<<<1, 64, 0, stream>>>(dh, dcur);
  deg_scatter_kernel<<<(N + 255) / 256, 256, 0, stream>>>(rowptr, dcur, perm, N);

  int ntiles = (N + 15) / 16;
  int nwaves = (N + 3) / 4;                 // 4 nodes per wave
  int nblocks = (nwaves * 64 + 255) / 256;
  const float* h_in = x;
  for (int l = 0; l < L; ++l) {
    float* h_out = (l == L - 1) ? (float*)d_out : ((l % 2 == 0) ? hA : hB);
    transform_kernel<<<512, 256, 0, stream>>>(
        h_in, Wl + (size_t)l * D * D, bl + (size_t)l * D,
        Wr + (size_t)l * D * D, br + (size_t)l * D, xlh, xrh, N, ntiles);
    edge_kernel<<<nblocks, 256, 0, stream>>>(
        xlh, xrh, h_in, rowptr, csr_src, perm, att + (size_t)l * D,
        bias + (size_t)l * D, h_out, N);
    h_in = h_out;
  }
}